// Round 17
// baseline (157.414 us; speedup 1.0000x reference)
//
#include <hip/hip_runtime.h>
#include <hip/hip_fp16.h>

#define F   128    // H*C
#define DIN 128
#define HID 128
#define NEG 0.2f
#define L2E 1.4426950408889634f
#define KNODE 8    // nodes per wave in k_node
#define CAP  64    // CSR slots per row (slot 0 = implicit self loop)
#define BW   64    // bucket width (nodes)
#define EPB  2048  // edges per sort block
#define NBP  800   // padded bin count (NBK=782 for N=50000)
#define PB   128   // prep blocks in k_fuseA

typedef _Float16 hvec2 __attribute__((ext_vector_type(2)));
typedef _Float16 half8 __attribute__((ext_vector_type(8)));
typedef float f32x4 __attribute__((ext_vector_type(4)));
union U2 { unsigned u; hvec2 v; };
union UH { _Float16 f; unsigned short u; };

// DPP add (VALU pipe)
template<int CTRL>
__device__ __forceinline__ float dpp_addf(float x){
    int t = __builtin_amdgcn_update_dpp(0, __float_as_int(x), CTRL, 0xF, 0xF, true);
    return x + __int_as_float(t);
}
// xor-4 lane swap via ds_swizzle (BitMode: xor=4, and=0x1F)
__device__ __forceinline__ float swz_xor4(float x){
    int t = __builtin_amdgcn_ds_swizzle(__float_as_int(x), 0x101F);
    return x + __int_as_float(t);
}

// ---- fuseA: blocks [0,PB) = prep + zero g_bits; blocks [PB,PB+B) = edge histogram ----
__global__ __launch_bounds__(256) void k_fuseA(
        const float* __restrict__ Wl, const float* __restrict__ Wr,
        const float* __restrict__ att,
        const float* __restrict__ bl, const float* __restrict__ br,
        unsigned short* __restrict__ WT, unsigned* __restrict__ att_h,
        float* __restrict__ bcat, unsigned* __restrict__ g_bits, int GF,
        const int* __restrict__ ei, unsigned* __restrict__ table, int E){
    __shared__ unsigned h[NBP];
    if ((int)blockIdx.x < PB){
        const int e = blockIdx.x * 256 + threadIdx.x;
        if (e < 32768){
            const int k = e >> 8, col = e & 255;
            const float w = (col < 128) ? Wl[k * 128 + col] : Wr[k * 128 + (col - 128)];
            UH u; u.f = (_Float16)w;
            WT[col * 128 + k] = u.u;
        }
        if (e < 64){
            float2 a2 = ((const float2*)att)[e];
            U2 r; r.v = hvec2{(_Float16)(a2.x * L2E), (_Float16)(a2.y * L2E)};
            att_h[e] = r.u;
        }
        if (e < 256) bcat[e] = (e < 128) ? bl[e] : br[e - 128];
        if (e < GF) g_bits[e] = 0u;
        return;
    }
    // histogram role
    const int blk = (int)blockIdx.x - PB;
    const int t = threadIdx.x;
    for (int b = t; b < NBP; b += 256) h[b] = 0u;
    __syncthreads();
    const int e0 = blk * EPB;
    const int e1 = (e0 + EPB < E) ? e0 + EPB : E;
    for (int e = e0 + t; e < e1; e += 256)
        atomicAdd(&h[ei[E + e] >> 6], 1u);
    __syncthreads();
    unsigned* row = table + (size_t)blk * NBP;
    for (int b = t; b < NBP; b += 256) row[b] = h[b];
}

// ---- sort pass 2a: per-bin parallel scan across blocks (one block per bin) ----
__global__ __launch_bounds__(512) void k_scanA(unsigned* __restrict__ table,
                        unsigned* __restrict__ btot, int B){
    __shared__ unsigned lds[512];
    const int bin = blockIdx.x;
    const int t = threadIdx.x;
    unsigned v = (t < B) ? table[(size_t)t * NBP + bin] : 0u;
    lds[t] = v; __syncthreads();
    unsigned acc = v;
    for (int off = 1; off < 512; off <<= 1){
        const unsigned add = (t >= off) ? lds[t - off] : 0u; __syncthreads();
        acc += add; lds[t] = acc; __syncthreads();
    }
    if (t < B) table[(size_t)t * NBP + bin] = acc - v;   // per-block exclusive offset
    if (t == B - 1) btot[bin] = acc;                     // bin total
}

// ---- sort pass 2b: exclusive scan of bin totals -> bbase ----
__global__ __launch_bounds__(1024) void k_scanB(const unsigned* __restrict__ btot,
                        unsigned* __restrict__ bbase, int NBK){
    __shared__ unsigned lds[1024];
    const int t = threadIdx.x;
    unsigned v = (t < NBK) ? btot[t] : 0u;
    lds[t] = v; __syncthreads();
    unsigned acc = v;
    for (int off = 1; off < 1024; off <<= 1){
        const unsigned add = (t >= off) ? lds[t - off] : 0u; __syncthreads();
        acc += add; lds[t] = acc; __syncthreads();
    }
    if (t < 1024 && t < NBP) bbase[t] = (t < NBK) ? acc - v : 0u;
}

// ---- sort pass 3: place edges densely by bucket (LDS cursors only) ----
__global__ __launch_bounds__(256) void k_eplace(const int* __restrict__ ei,
                        const unsigned* __restrict__ table, const unsigned* __restrict__ bbase,
                        unsigned* __restrict__ bucket, int E){
    __shared__ unsigned curs[NBP];
    const int t = threadIdx.x;
    const unsigned* row = table + (size_t)blockIdx.x * NBP;
    for (int b = t; b < NBP; b += 256) curs[b] = row[b] + bbase[b];
    __syncthreads();
    const int e0 = blockIdx.x * EPB;
    const int e1 = (e0 + EPB < E) ? e0 + EPB : E;
    for (int e = e0 + t; e < e1; e += 256){
        const int src = ei[e];
        const int dst = ei[E + e];
        const unsigned pos = atomicAdd(&curs[dst >> 6], 1u);
        bucket[pos] = ((unsigned)src << 6) | (unsigned)(dst & 63);
    }
}

// ---- fuseB: blocks [0,NBK) = per-bucket CSR scatter; blocks [NBK,..) = MFMA transform ----
__global__ __launch_bounds__(256) void k_fuseB(
        const unsigned* __restrict__ bbase, const unsigned* __restrict__ btot,
        const unsigned* __restrict__ bucket, unsigned* __restrict__ cnt,
        int* __restrict__ slots, int N, int NBK,
        const float* __restrict__ x, const unsigned short* __restrict__ WT,
        const float* __restrict__ bcat,
        unsigned short* __restrict__ xl_s, unsigned short* __restrict__ xr_s){
    __shared__ unsigned lc[BW];
    if ((int)blockIdx.x < NBK){
        const int b = blockIdx.x;
        const int t = threadIdx.x;
        if (t < BW) lc[t] = 0u;
        __syncthreads();
        const int base = b << 6;
        const unsigned s0 = bbase[b];
        const int n = (int)btot[b];
        for (int e = t; e < n; e += 256){
            const unsigned w = bucket[s0 + e];
            const int d = (int)(w & 63u);
            const unsigned pos = atomicAdd(&lc[d], 1u);
            if (pos < CAP - 1) slots[((size_t)(base + d) << 6) + 1 + pos] = (int)(w >> 6);
        }
        __syncthreads();
        if (t < BW && base + t < N) cnt[base + t] = lc[t];
        return;
    }
    // ---- MFMA transform role ----
    const int mb = (int)blockIdx.x - NBK;
    const int t = threadIdx.x;
    const int w = t >> 6, lane = t & 63;
    const int li = lane & 15, hi = lane >> 4;
    const int rowA = mb * 64 + w * 16 + li;
    const int rA = (rowA < N) ? rowA : N - 1;
    f32x4 acc[16];
    #pragma unroll
    for (int c = 0; c < 16; ++c) acc[c] = f32x4{0.f, 0.f, 0.f, 0.f};
    #pragma unroll
    for (int kt = 0; kt < 4; ++kt){
        const int k0 = kt * 32 + hi * 8;
        const float4 f0 = *(const float4*)(x + (size_t)rA * DIN + k0);
        const float4 f1 = *(const float4*)(x + (size_t)rA * DIN + k0 + 4);
        half8 b;
        b[0] = (_Float16)f0.x; b[1] = (_Float16)f0.y; b[2] = (_Float16)f0.z; b[3] = (_Float16)f0.w;
        b[4] = (_Float16)f1.x; b[5] = (_Float16)f1.y; b[6] = (_Float16)f1.z; b[7] = (_Float16)f1.w;
        #pragma unroll
        for (int c = 0; c < 16; ++c){
            const half8 a = *(const half8*)(WT + (size_t)(c * 16 + li) * 128 + k0);
            acc[c] = __builtin_amdgcn_mfma_f32_16x16x32_f16(a, b, acc[c], 0, 0, 0);
        }
    }
    if (rowA < N){
        #pragma unroll
        for (int c = 0; c < 16; ++c){
            const int col0 = c * 16 + hi * 4;
            const float4 bv = *(const float4*)(bcat + col0);
            UH p0, p1, p2, p3;
            p0.f = (_Float16)(acc[c][0] + bv.x);
            p1.f = (_Float16)(acc[c][1] + bv.y);
            p2.f = (_Float16)(acc[c][2] + bv.z);
            p3.f = (_Float16)(acc[c][3] + bv.w);
            uint2 val;
            val.x = (unsigned)p0.u | ((unsigned)p1.u << 16);
            val.y = (unsigned)p2.u | ((unsigned)p3.u << 16);
            if (col0 < 128) *(uint2*)(xl_s + (size_t)rowA * F + col0)         = val;
            else            *(uint2*)(xr_s + (size_t)rowA * F + (col0 - 128)) = val;
        }
    }
}

// ---- per-node GATv2: 2 edges/wave (half-wave split), 4ch/lane, KNODE nodes/wave ----
__global__ void k_node(const unsigned* __restrict__ xl_h, const unsigned* __restrict__ xr_h,
                       const int* __restrict__ slots, const unsigned* __restrict__ cnt,
                       const unsigned* __restrict__ att_h, const float* __restrict__ bias,
                       const int* __restrict__ batch, unsigned* __restrict__ g_bits, int N){
    const int wid  = (int)(((long long)blockIdx.x * blockDim.x + threadIdx.x) >> 6);
    const int lane = threadIdx.x & 63;
    const int half = lane >> 5;          // 0: edge e, 1: edge e+1
    const int cl   = lane & 31;          // channel quad: ch 4cl..4cl+3
    const int i0 = wid * KNODE;
    if (i0 >= N) return;
    const uint2 at2 = ((const uint2*)att_h)[cl];
    U2 at0, at1; at0.u = at2.x; at1.u = at2.y;
    const float4 bz = ((const float4*)bias)[cl];
    const hvec2 neg2 = {(_Float16)NEG, (_Float16)NEG};
    float pool0 = 0.f, pool1 = 0.f, pool2 = 0.f, pool3 = 0.f;
    int curg = __builtin_amdgcn_readfirstlane(batch[i0]);
    const int iend = (i0 + KNODE < N) ? i0 + KNODE : N;
    const uint2* xl2 = (const uint2*)xl_h;

    for (int i = i0; i < iend; ++i){
        const int g = __builtin_amdgcn_readfirstlane(batch[i]);
        if (g != curg){
            if (half == 0){
                unsigned* gb = &g_bits[curg * F + 4 * cl];
                atomicMax(&gb[0], __float_as_uint(pool0));
                atomicMax(&gb[1], __float_as_uint(pool1));
                atomicMax(&gb[2], __float_as_uint(pool2));
                atomicMax(&gb[3], __float_as_uint(pool3));
            }
            pool0 = pool1 = pool2 = pool3 = 0.f; curg = g;
        }
        const int rs = i << 6;
        int dt = (int)cnt[i] + 1;           // incl. implicit self loop (slot 0)
        if (dt > CAP) dt = CAP;
        const uint2 xr2 = ((const uint2*)xr_h)[(size_t)i * 32 + cl];
        U2 xr0, xr1; xr0.u = xr2.x; xr1.u = xr2.y;

        // 4 ILP chains, each proc2 handles 2 edges
        float d0=0.f,d1=0.f,d2=0.f,d3=0.f;
        float a00=0.f,a01=0.f,a02=0.f,a03=0.f;
        float a10=0.f,a11=0.f,a12=0.f,a13=0.f;
        float a20=0.f,a21=0.f,a22=0.f,a23=0.f;
        float a30=0.f,a31=0.f,a32=0.f,a33=0.f;

        // lane e holds src of edge e; lane 0 = implicit self loop
        const int my_src = (lane > 0 && lane < dt) ? slots[rs + lane] : i;

        auto proc2 = [&](int e, float& d_, float& x0, float& x1, float& x2, float& x3){
            const int srcv = __shfl(my_src, e + half, 64);
            const uint2 xlv = xl2[(size_t)srcv * 32 + cl];
            U2 b0, b1; b0.u = xlv.x; b1.u = xlv.y;
            hvec2 z0 = b0.v + xr0.v;
            hvec2 z1 = b1.v + xr1.v;
            hvec2 r0 = __builtin_elementwise_max(z0, z0 * neg2);
            hvec2 r1 = __builtin_elementwise_max(z1, z1 * neg2);
#if __has_builtin(__builtin_amdgcn_fdot2)
            float s = __builtin_amdgcn_fdot2(r0, at0.v, 0.f, false);
            s = __builtin_amdgcn_fdot2(r1, at1.v, s, false);
#else
            float s = (float)r0.x * (float)at0.v.x + (float)r0.y * (float)at0.v.y
                    + (float)r1.x * (float)at1.v.x + (float)r1.y * (float)at1.v.y;
#endif
            s = dpp_addf<0xB1>(s);   // xor 1
            s = dpp_addf<0x4E>(s);   // xor 2
            s = swz_xor4(s);         // xor 4  -> 8-lane head sum (32 ch)
            const float p = (e + half < dt) ? exp2f(s) : 0.f;
            d_ += p;
            x0 = fmaf(p, (float)b0.v.x, x0);
            x1 = fmaf(p, (float)b0.v.y, x1);
            x2 = fmaf(p, (float)b1.v.x, x2);
            x3 = fmaf(p, (float)b1.v.y, x3);
        };

        int e = 0;
        for (; e + 7 < dt; e += 8){
            proc2(e,     d0, a00, a01, a02, a03);
            proc2(e + 2, d1, a10, a11, a12, a13);
            proc2(e + 4, d2, a20, a21, a22, a23);
            proc2(e + 6, d3, a30, a31, a32, a33);
        }
        for (; e < dt; e += 2)
            proc2(e, d0, a00, a01, a02, a03);

        // merge chains + fold across halves
        float d = (d0 + d1) + (d2 + d3);
        float c0 = (a00 + a10) + (a20 + a30);
        float c1 = (a01 + a11) + (a21 + a31);
        float c2 = (a02 + a12) + (a22 + a32);
        float c3 = (a03 + a13) + (a23 + a33);
        d  += __shfl_xor(d, 32, 64);
        c0 += __shfl_xor(c0, 32, 64);
        c1 += __shfl_xor(c1, 32, 64);
        c2 += __shfl_xor(c2, 32, 64);
        c3 += __shfl_xor(c3, 32, 64);
        const float inv = 1.f / (d + 1e-16f);
        pool0 = fmaxf(pool0, fmaxf(fmaf(c0, inv, bz.x), 0.f));
        pool1 = fmaxf(pool1, fmaxf(fmaf(c1, inv, bz.y), 0.f));
        pool2 = fmaxf(pool2, fmaxf(fmaf(c2, inv, bz.z), 0.f));
        pool3 = fmaxf(pool3, fmaxf(fmaf(c3, inv, bz.w), 0.f));
    }
    if (half == 0){
        unsigned* gb = &g_bits[curg * F + 4 * cl];
        atomicMax(&gb[0], __float_as_uint(pool0));
        atomicMax(&gb[1], __float_as_uint(pool1));
        atomicMax(&gb[2], __float_as_uint(pool2));
        atomicMax(&gb[3], __float_as_uint(pool3));
    }
}

// ---- dueling heads, one block (128 thr) per graph ----
__global__ void k_dueling(const float* __restrict__ g,
                          const float* __restrict__ Wq1, const float* __restrict__ bq1,
                          const float* __restrict__ Wq2, const float* __restrict__ bq2,
                          const float* __restrict__ Wv1, const float* __restrict__ bv1,
                          const float* __restrict__ Wv2, const float* __restrict__ bv2,
                          float* __restrict__ out){
    __shared__ float gs[F], red0[128], red1[128], red2[128];
    const int t = threadIdx.x, gi = blockIdx.x;
    gs[t] = g[gi * F + t];
    __syncthreads();
    float aq = bq1[t], av = bv1[t];
    for (int k = 0; k < F; ++k){
        aq = fmaf(gs[k], Wq1[k * HID + t], aq);
        av = fmaf(gs[k], Wv1[k * HID + t], av);
    }
    aq = aq > 0.f ? aq : 0.f;
    av = av > 0.f ? av : 0.f;
    red0[t] = aq * Wq2[t * 2 + 0];
    red1[t] = aq * Wq2[t * 2 + 1];
    red2[t] = av * Wv2[t];
    __syncthreads();
    for (int off = 64; off > 0; off >>= 1){
        if (t < off){ red0[t] += red0[t + off]; red1[t] += red1[t + off]; red2[t] += red2[t + off]; }
        __syncthreads();
    }
    if (t == 0){
        const float q0 = red0[0] + bq2[0];
        const float q1 = red1[0] + bq2[1];
        const float v  = red2[0] + bv2[0];
        out[gi * 2 + 0] = 0.5f * (q0 - q1) + v;
        out[gi * 2 + 1] = 0.5f * (q1 - q0) + v;
    }
}

extern "C" void kernel_launch(void* const* d_in, const int* in_sizes, int n_in,
                              void* d_out, int out_size, void* d_ws, size_t ws_size,
                              hipStream_t stream) {
    const float* x    = (const float*)d_in[0];
    const float* Wl   = (const float*)d_in[1];
    const float* bl   = (const float*)d_in[2];
    const float* Wr   = (const float*)d_in[3];
    const float* br   = (const float*)d_in[4];
    const float* att  = (const float*)d_in[5];
    const float* bias = (const float*)d_in[6];
    const float* Wq1  = (const float*)d_in[7];
    const float* bq1  = (const float*)d_in[8];
    const float* Wq2  = (const float*)d_in[9];
    const float* bq2  = (const float*)d_in[10];
    const float* Wv1  = (const float*)d_in[11];
    const float* bv1  = (const float*)d_in[12];
    const float* Wv2  = (const float*)d_in[13];
    const float* bv2  = (const float*)d_in[14];
    const int*   ei   = (const int*)d_in[15];
    const int*   batch= (const int*)d_in[16];
    float* out = (float*)d_out;

    const int N  = in_sizes[0] / DIN;
    const int E  = in_sizes[15] / 2;
    const int Gg = out_size / 2;
    const int GF = Gg * F;
    const int NBK = (N + BW - 1) / BW;           // buckets (<= NBP)
    const int B   = (E + EPB - 1) / EPB;         // sort blocks (<= 512)
    const int MMB = (N + 63) / 64;               // mfma-transform blocks

    // workspace layout (u32 words)
    unsigned* xl_h   = (unsigned*)d_ws;                    // N*64
    unsigned* xr_h   = xl_h + (size_t)N * 64;              // N*64
    unsigned* att_h  = xr_h + (size_t)N * 64;              // 64
    unsigned* WT     = att_h + 64;                         // 16384 (256x128 ushort)
    float*    bcat   = (float*)(WT + 16384);               // 256
    unsigned* g_bits = (unsigned*)(bcat + 256);            // GF (zeroed in fuseA)
    unsigned* cnt    = g_bits + GF;                        // N (written by fuseB)
    unsigned* bbase  = cnt + N;                            // NBP
    unsigned* btot   = bbase + NBP;                        // NBP
    unsigned* table  = btot + NBP;                         // B*NBP
    unsigned* bucket = table + (size_t)B * NBP;            // E
    int*      slots  = (int*)(bucket + E);                 // N*64

    k_fuseA<<<PB + B, 256, 0, stream>>>(Wl, Wr, att, bl, br, (unsigned short*)WT,
                                        att_h, bcat, g_bits, GF, ei, table, E);
    k_scanA<<<NBK, 512, 0, stream>>>(table, btot, B);
    k_scanB<<<1, 1024, 0, stream>>>(btot, bbase, NBK);
    k_eplace<<<B, 256, 0, stream>>>(ei, table, bbase, bucket, E);
    k_fuseB<<<NBK + MMB, 256, 0, stream>>>(bbase, btot, bucket, cnt, slots, N, NBK,
                                           x, (const unsigned short*)WT, bcat,
                                           (unsigned short*)xl_h, (unsigned short*)xr_h);
    {
        const long long waves = (N + KNODE - 1) / KNODE;
        const long long thr = waves * 64;
        k_node<<<(unsigned)((thr + 255) / 256), 256, 0, stream>>>(
            xl_h, xr_h, slots, cnt, att_h, bias, batch, g_bits, N);
    }
    k_dueling<<<Gg, 128, 0, stream>>>((const float*)g_bits, Wq1, bq1, Wq2, bq2,
                                      Wv1, bv1, Wv2, bv2, out);
}

// Round 18
// 144.388 us; speedup vs baseline: 1.0902x; 1.0902x over previous
//
#include <hip/hip_runtime.h>
#include <hip/hip_fp16.h>

#define F   128    // H*C
#define DIN 128
#define HID 128
#define NEG 0.2f
#define L2E 1.4426950408889634f
#define KNODE 8    // nodes per wave in k_node
#define CAP  64    // CSR slots per row (slot 0 = implicit self loop)
#define BW   64    // bucket width (nodes)
#define EPB  2048  // edges per sort block
#define NBP  800   // padded bin count (NBK=782 for N=50000)
#define PB   128   // prep blocks in k_fuseA

typedef _Float16 hvec2 __attribute__((ext_vector_type(2)));
typedef _Float16 half8 __attribute__((ext_vector_type(8)));
typedef float f32x4 __attribute__((ext_vector_type(4)));
union U2 { unsigned u; hvec2 v; };
union UH { _Float16 f; unsigned short u; };

// DPP add (VALU pipe); row = 16 lanes on CDNA
template<int CTRL>
__device__ __forceinline__ float dpp_addf(float x){
    int t = __builtin_amdgcn_update_dpp(0, __float_as_int(x), CTRL, 0xF, 0xF, true);
    return x + __int_as_float(t);
}

// ---- fuseA: blocks [0,PB) = prep + zero g_bits; blocks [PB,PB+B) = edge histogram ----
__global__ __launch_bounds__(256) void k_fuseA(
        const float* __restrict__ Wl, const float* __restrict__ Wr,
        const float* __restrict__ att,
        const float* __restrict__ bl, const float* __restrict__ br,
        unsigned short* __restrict__ WT, unsigned* __restrict__ att_h,
        float* __restrict__ bcat, unsigned* __restrict__ g_bits, int GF,
        const int* __restrict__ ei, unsigned* __restrict__ table, int E){
    __shared__ unsigned h[NBP];
    if ((int)blockIdx.x < PB){
        const int e = blockIdx.x * 256 + threadIdx.x;
        if (e < 32768){
            const int k = e >> 8, col = e & 255;
            const float w = (col < 128) ? Wl[k * 128 + col] : Wr[k * 128 + (col - 128)];
            UH u; u.f = (_Float16)w;
            WT[col * 128 + k] = u.u;
        }
        if (e < 64){
            float2 a2 = ((const float2*)att)[e];
            U2 r; r.v = hvec2{(_Float16)(a2.x * L2E), (_Float16)(a2.y * L2E)};
            att_h[e] = r.u;
        }
        if (e < 256) bcat[e] = (e < 128) ? bl[e] : br[e - 128];
        if (e < GF) g_bits[e] = 0u;
        return;
    }
    // histogram role
    const int blk = (int)blockIdx.x - PB;
    const int t = threadIdx.x;
    for (int b = t; b < NBP; b += 256) h[b] = 0u;
    __syncthreads();
    const int e0 = blk * EPB;
    const int e1 = (e0 + EPB < E) ? e0 + EPB : E;
    for (int e = e0 + t; e < e1; e += 256)
        atomicAdd(&h[ei[E + e] >> 6], 1u);
    __syncthreads();
    unsigned* row = table + (size_t)blk * NBP;
    for (int b = t; b < NBP; b += 256) row[b] = h[b];
}

// ---- sort pass 2a: per-bin parallel scan across blocks (one block per bin) ----
__global__ __launch_bounds__(512) void k_scanA(unsigned* __restrict__ table,
                        unsigned* __restrict__ btot, int B){
    __shared__ unsigned lds[512];
    const int bin = blockIdx.x;
    const int t = threadIdx.x;
    unsigned v = (t < B) ? table[(size_t)t * NBP + bin] : 0u;
    lds[t] = v; __syncthreads();
    unsigned acc = v;
    for (int off = 1; off < 512; off <<= 1){
        const unsigned add = (t >= off) ? lds[t - off] : 0u; __syncthreads();
        acc += add; lds[t] = acc; __syncthreads();
    }
    if (t < B) table[(size_t)t * NBP + bin] = acc - v;   // per-block exclusive offset
    if (t == B - 1) btot[bin] = acc;                     // bin total
}

// ---- sort pass 2b: exclusive scan of bin totals -> bbase ----
__global__ __launch_bounds__(1024) void k_scanB(const unsigned* __restrict__ btot,
                        unsigned* __restrict__ bbase, int NBK){
    __shared__ unsigned lds[1024];
    const int t = threadIdx.x;
    unsigned v = (t < NBK) ? btot[t] : 0u;
    lds[t] = v; __syncthreads();
    unsigned acc = v;
    for (int off = 1; off < 1024; off <<= 1){
        const unsigned add = (t >= off) ? lds[t - off] : 0u; __syncthreads();
        acc += add; lds[t] = acc; __syncthreads();
    }
    if (t < 1024 && t < NBP) bbase[t] = (t < NBK) ? acc - v : 0u;
}

// ---- sort pass 3: place edges densely by bucket (LDS cursors only) ----
__global__ __launch_bounds__(256) void k_eplace(const int* __restrict__ ei,
                        const unsigned* __restrict__ table, const unsigned* __restrict__ bbase,
                        unsigned* __restrict__ bucket, int E){
    __shared__ unsigned curs[NBP];
    const int t = threadIdx.x;
    const unsigned* row = table + (size_t)blockIdx.x * NBP;
    for (int b = t; b < NBP; b += 256) curs[b] = row[b] + bbase[b];
    __syncthreads();
    const int e0 = blockIdx.x * EPB;
    const int e1 = (e0 + EPB < E) ? e0 + EPB : E;
    for (int e = e0 + t; e < e1; e += 256){
        const int src = ei[e];
        const int dst = ei[E + e];
        const unsigned pos = atomicAdd(&curs[dst >> 6], 1u);
        bucket[pos] = ((unsigned)src << 6) | (unsigned)(dst & 63);
    }
}

// ---- fuseB: blocks [0,NBK) = per-bucket CSR scatter; blocks [NBK,..) = MFMA transform ----
__global__ __launch_bounds__(256) void k_fuseB(
        const unsigned* __restrict__ bbase, const unsigned* __restrict__ btot,
        const unsigned* __restrict__ bucket, unsigned* __restrict__ cnt,
        int* __restrict__ slots, int N, int NBK,
        const float* __restrict__ x, const unsigned short* __restrict__ WT,
        const float* __restrict__ bcat,
        unsigned short* __restrict__ xl_s, unsigned short* __restrict__ xr_s){
    __shared__ unsigned lc[BW];
    if ((int)blockIdx.x < NBK){
        const int b = blockIdx.x;
        const int t = threadIdx.x;
        if (t < BW) lc[t] = 0u;
        __syncthreads();
        const int base = b << 6;
        const unsigned s0 = bbase[b];
        const int n = (int)btot[b];
        for (int e = t; e < n; e += 256){
            const unsigned w = bucket[s0 + e];
            const int d = (int)(w & 63u);
            const unsigned pos = atomicAdd(&lc[d], 1u);
            if (pos < CAP - 1) slots[((size_t)(base + d) << 6) + 1 + pos] = (int)(w >> 6);
        }
        __syncthreads();
        if (t < BW && base + t < N) cnt[base + t] = lc[t];
        return;
    }
    // ---- MFMA transform role ----
    const int mb = (int)blockIdx.x - NBK;
    const int t = threadIdx.x;
    const int w = t >> 6, lane = t & 63;
    const int li = lane & 15, hi = lane >> 4;
    const int rowA = mb * 64 + w * 16 + li;
    const int rA = (rowA < N) ? rowA : N - 1;
    f32x4 acc[16];
    #pragma unroll
    for (int c = 0; c < 16; ++c) acc[c] = f32x4{0.f, 0.f, 0.f, 0.f};
    #pragma unroll
    for (int kt = 0; kt < 4; ++kt){
        const int k0 = kt * 32 + hi * 8;
        const float4 f0 = *(const float4*)(x + (size_t)rA * DIN + k0);
        const float4 f1 = *(const float4*)(x + (size_t)rA * DIN + k0 + 4);
        half8 b;
        b[0] = (_Float16)f0.x; b[1] = (_Float16)f0.y; b[2] = (_Float16)f0.z; b[3] = (_Float16)f0.w;
        b[4] = (_Float16)f1.x; b[5] = (_Float16)f1.y; b[6] = (_Float16)f1.z; b[7] = (_Float16)f1.w;
        #pragma unroll
        for (int c = 0; c < 16; ++c){
            const half8 a = *(const half8*)(WT + (size_t)(c * 16 + li) * 128 + k0);
            acc[c] = __builtin_amdgcn_mfma_f32_16x16x32_f16(a, b, acc[c], 0, 0, 0);
        }
    }
    if (rowA < N){
        #pragma unroll
        for (int c = 0; c < 16; ++c){
            const int col0 = c * 16 + hi * 4;
            const float4 bv = *(const float4*)(bcat + col0);
            UH p0, p1, p2, p3;
            p0.f = (_Float16)(acc[c][0] + bv.x);
            p1.f = (_Float16)(acc[c][1] + bv.y);
            p2.f = (_Float16)(acc[c][2] + bv.z);
            p3.f = (_Float16)(acc[c][3] + bv.w);
            uint2 val;
            val.x = (unsigned)p0.u | ((unsigned)p1.u << 16);
            val.y = (unsigned)p2.u | ((unsigned)p3.u << 16);
            if (col0 < 128) *(uint2*)(xl_s + (size_t)rowA * F + col0)         = val;
            else            *(uint2*)(xr_s + (size_t)rowA * F + (col0 - 128)) = val;
        }
    }
}

// ---- fused per-node GATv2: KNODE nodes/wave, ILP8, register-pooled max ----
__global__ void k_node(const unsigned* __restrict__ xl_h, const unsigned* __restrict__ xr_h,
                       const int* __restrict__ slots, const unsigned* __restrict__ cnt,
                       const unsigned* __restrict__ att_h, const float* __restrict__ bias,
                       const int* __restrict__ batch, unsigned* __restrict__ g_bits, int N){
    const int wid  = (int)(((long long)blockIdx.x * blockDim.x + threadIdx.x) >> 6);
    const int lane = threadIdx.x & 63;
    const int i0 = wid * KNODE;
    if (i0 >= N) return;
    U2 atv; atv.u = att_h[lane];
    const float2 bz = ((const float2*)bias)[lane];
    const hvec2 neg2 = {(_Float16)NEG, (_Float16)NEG};
    float pool0 = 0.f, pool1 = 0.f;
    int curg = __builtin_amdgcn_readfirstlane(batch[i0]);
    const int iend = (i0 + KNODE < N) ? i0 + KNODE : N;

    for (int i = i0; i < iend; ++i){
        const int g = __builtin_amdgcn_readfirstlane(batch[i]);
        if (g != curg){
            atomicMax(&g_bits[curg * F + 2 * lane],     __float_as_uint(pool0));
            atomicMax(&g_bits[curg * F + 2 * lane + 1], __float_as_uint(pool1));
            pool0 = 0.f; pool1 = 0.f; curg = g;
        }
        const int rs = i << 6;
        int dt = (int)cnt[i] + 1;           // incl. implicit self loop (slot 0)
        if (dt > CAP) dt = CAP;
        U2 xrv; xrv.u = xr_h[(size_t)i * 64 + lane];

        float d0=0.f,d1=0.f,d2=0.f,d3=0.f,d4=0.f,d5=0.f,d6=0.f,d7=0.f;
        float ax0=0.f,ax1=0.f,ax2=0.f,ax3=0.f,ax4=0.f,ax5=0.f,ax6=0.f,ax7=0.f;
        float ay0=0.f,ay1=0.f,ay2=0.f,ay3=0.f,ay4=0.f,ay5=0.f,ay6=0.f,ay7=0.f;

        auto proc = [&](unsigned hv, float& d_, float& ax_, float& ay_){
            U2 xlv; xlv.u = hv;
            hvec2 z = xlv.v + xrv.v;
            hvec2 r = __builtin_elementwise_max(z, z * neg2);   // LeakyReLU
#if __has_builtin(__builtin_amdgcn_fdot2)
            float s = __builtin_amdgcn_fdot2(r, atv.v, 0.f, false);
#else
            float s = fmaf((float)r.x, (float)atv.v.x, (float)r.y * (float)atv.v.y);
#endif
            s = dpp_addf<0xB1>(s);    // xor 1
            s = dpp_addf<0x4E>(s);    // xor 2
            s = dpp_addf<0x124>(s);   // row_ror:4
            s = dpp_addf<0x128>(s);   // row_ror:8  -> 16-lane head sum
            const float p = exp2f(s);
            d_ += p;
            ax_ = fmaf(p, (float)xlv.v.x, ax_);
            ay_ = fmaf(p, (float)xlv.v.y, ay_);
        };

        // lane e holds src of edge e; lane 0 = implicit self loop
        const int my_src = (lane > 0 && lane < dt) ? slots[rs + lane] : i;
        int e = 0;
        for (; e + 7 < dt; e += 8){
            const int s0 = __builtin_amdgcn_readlane(my_src, e);
            const int s1 = __builtin_amdgcn_readlane(my_src, e + 1);
            const int s2 = __builtin_amdgcn_readlane(my_src, e + 2);
            const int s3 = __builtin_amdgcn_readlane(my_src, e + 3);
            const int s4 = __builtin_amdgcn_readlane(my_src, e + 4);
            const int s5 = __builtin_amdgcn_readlane(my_src, e + 5);
            const int s6 = __builtin_amdgcn_readlane(my_src, e + 6);
            const int s7 = __builtin_amdgcn_readlane(my_src, e + 7);
            const unsigned h0 = xl_h[(size_t)s0 * 64 + lane];
            const unsigned h1 = xl_h[(size_t)s1 * 64 + lane];
            const unsigned h2 = xl_h[(size_t)s2 * 64 + lane];
            const unsigned h3 = xl_h[(size_t)s3 * 64 + lane];
            const unsigned h4 = xl_h[(size_t)s4 * 64 + lane];
            const unsigned h5 = xl_h[(size_t)s5 * 64 + lane];
            const unsigned h6 = xl_h[(size_t)s6 * 64 + lane];
            const unsigned h7 = xl_h[(size_t)s7 * 64 + lane];
            proc(h0, d0, ax0, ay0); proc(h1, d1, ax1, ay1);
            proc(h2, d2, ax2, ay2); proc(h3, d3, ax3, ay3);
            proc(h4, d4, ax4, ay4); proc(h5, d5, ax5, ay5);
            proc(h6, d6, ax6, ay6); proc(h7, d7, ax7, ay7);
        }
        for (; e + 3 < dt; e += 4){
            const int s0 = __builtin_amdgcn_readlane(my_src, e);
            const int s1 = __builtin_amdgcn_readlane(my_src, e + 1);
            const int s2 = __builtin_amdgcn_readlane(my_src, e + 2);
            const int s3 = __builtin_amdgcn_readlane(my_src, e + 3);
            const unsigned h0 = xl_h[(size_t)s0 * 64 + lane];
            const unsigned h1 = xl_h[(size_t)s1 * 64 + lane];
            const unsigned h2 = xl_h[(size_t)s2 * 64 + lane];
            const unsigned h3 = xl_h[(size_t)s3 * 64 + lane];
            proc(h0, d0, ax0, ay0); proc(h1, d1, ax1, ay1);
            proc(h2, d2, ax2, ay2); proc(h3, d3, ax3, ay3);
        }
        for (; e < dt; ++e){
            const int s0 = __builtin_amdgcn_readlane(my_src, e);
            proc(xl_h[(size_t)s0 * 64 + lane], d0, ax0, ay0);
        }

        const float dsum = ((d0 + d1) + (d2 + d3)) + ((d4 + d5) + (d6 + d7));
        const float ax = ((ax0 + ax1) + (ax2 + ax3)) + ((ax4 + ax5) + (ax6 + ax7));
        const float ay = ((ay0 + ay1) + (ay2 + ay3)) + ((ay4 + ay5) + (ay6 + ay7));
        const float inv = 1.f / (dsum + 1e-16f);
        pool0 = fmaxf(pool0, fmaxf(fmaf(ax, inv, bz.x), 0.f));
        pool1 = fmaxf(pool1, fmaxf(fmaf(ay, inv, bz.y), 0.f));
    }
    atomicMax(&g_bits[curg * F + 2 * lane],     __float_as_uint(pool0));
    atomicMax(&g_bits[curg * F + 2 * lane + 1], __float_as_uint(pool1));
}

// ---- dueling heads, one block (128 thr) per graph ----
__global__ void k_dueling(const float* __restrict__ g,
                          const float* __restrict__ Wq1, const float* __restrict__ bq1,
                          const float* __restrict__ Wq2, const float* __restrict__ bq2,
                          const float* __restrict__ Wv1, const float* __restrict__ bv1,
                          const float* __restrict__ Wv2, const float* __restrict__ bv2,
                          float* __restrict__ out){
    __shared__ float gs[F], red0[128], red1[128], red2[128];
    const int t = threadIdx.x, gi = blockIdx.x;
    gs[t] = g[gi * F + t];
    __syncthreads();
    float aq = bq1[t], av = bv1[t];
    for (int k = 0; k < F; ++k){
        aq = fmaf(gs[k], Wq1[k * HID + t], aq);
        av = fmaf(gs[k], Wv1[k * HID + t], av);
    }
    aq = aq > 0.f ? aq : 0.f;
    av = av > 0.f ? av : 0.f;
    red0[t] = aq * Wq2[t * 2 + 0];
    red1[t] = aq * Wq2[t * 2 + 1];
    red2[t] = av * Wv2[t];
    __syncthreads();
    for (int off = 64; off > 0; off >>= 1){
        if (t < off){ red0[t] += red0[t + off]; red1[t] += red1[t + off]; red2[t] += red2[t + off]; }
        __syncthreads();
    }
    if (t == 0){
        const float q0 = red0[0] + bq2[0];
        const float q1 = red1[0] + bq2[1];
        const float v  = red2[0] + bv2[0];
        out[gi * 2 + 0] = 0.5f * (q0 - q1) + v;
        out[gi * 2 + 1] = 0.5f * (q1 - q0) + v;
    }
}

extern "C" void kernel_launch(void* const* d_in, const int* in_sizes, int n_in,
                              void* d_out, int out_size, void* d_ws, size_t ws_size,
                              hipStream_t stream) {
    const float* x    = (const float*)d_in[0];
    const float* Wl   = (const float*)d_in[1];
    const float* bl   = (const float*)d_in[2];
    const float* Wr   = (const float*)d_in[3];
    const float* br   = (const float*)d_in[4];
    const float* att  = (const float*)d_in[5];
    const float* bias = (const float*)d_in[6];
    const float* Wq1  = (const float*)d_in[7];
    const float* bq1  = (const float*)d_in[8];
    const float* Wq2  = (const float*)d_in[9];
    const float* bq2  = (const float*)d_in[10];
    const float* Wv1  = (const float*)d_in[11];
    const float* bv1  = (const float*)d_in[12];
    const float* Wv2  = (const float*)d_in[13];
    const float* bv2  = (const float*)d_in[14];
    const int*   ei   = (const int*)d_in[15];
    const int*   batch= (const int*)d_in[16];
    float* out = (float*)d_out;

    const int N  = in_sizes[0] / DIN;
    const int E  = in_sizes[15] / 2;
    const int Gg = out_size / 2;
    const int GF = Gg * F;
    const int NBK = (N + BW - 1) / BW;           // buckets (<= NBP)
    const int B   = (E + EPB - 1) / EPB;         // sort blocks (<= 512)
    const int MMB = (N + 63) / 64;               // mfma-transform blocks

    // workspace layout (u32 words)
    unsigned* xl_h   = (unsigned*)d_ws;                    // N*64
    unsigned* xr_h   = xl_h + (size_t)N * 64;              // N*64
    unsigned* att_h  = xr_h + (size_t)N * 64;              // 64
    unsigned* WT     = att_h + 64;                         // 16384 (256x128 ushort)
    float*    bcat   = (float*)(WT + 16384);               // 256
    unsigned* g_bits = (unsigned*)(bcat + 256);            // GF (zeroed in fuseA)
    unsigned* cnt    = g_bits + GF;                        // N (written by fuseB)
    unsigned* bbase  = cnt + N;                            // NBP
    unsigned* btot   = bbase + NBP;                        // NBP
    unsigned* table  = btot + NBP;                         // B*NBP
    unsigned* bucket = table + (size_t)B * NBP;            // E
    int*      slots  = (int*)(bucket + E);                 // N*64

    k_fuseA<<<PB + B, 256, 0, stream>>>(Wl, Wr, att, bl, br, (unsigned short*)WT,
                                        att_h, bcat, g_bits, GF, ei, table, E);
    k_scanA<<<NBK, 512, 0, stream>>>(table, btot, B);
    k_scanB<<<1, 1024, 0, stream>>>(btot, bbase, NBK);
    k_eplace<<<B, 256, 0, stream>>>(ei, table, bbase, bucket, E);
    k_fuseB<<<NBK + MMB, 256, 0, stream>>>(bbase, btot, bucket, cnt, slots, N, NBK,
                                           x, (const unsigned short*)WT, bcat,
                                           (unsigned short*)xl_h, (unsigned short*)xr_h);
    {
        const long long waves = (N + KNODE - 1) / KNODE;
        const long long thr = waves * 64;
        k_node<<<(unsigned)((thr + 255) / 256), 256, 0, stream>>>(
            xl_h, xr_h, slots, cnt, att_h, bias, batch, g_bits, N);
    }
    k_dueling<<<Gg, 128, 0, stream>>>((const float*)g_bits, Wq1, bq1, Wq2, bq2,
                                      Wv1, bv1, Wv2, bv2, out);
}